// Round 5
// baseline (388.189 us; speedup 1.0000x reference)
//
#include <hip/hip_runtime.h>

#define FEAT 256
#define HID 128
#define NKEYS 2

typedef __bf16 bf16x8 __attribute__((ext_vector_type(8)));
typedef float f32x16 __attribute__((ext_vector_type(16)));

#define LDS_ROW 1040   // 1024 B row + 16 B pad (keeps b128 reads bank-uniform)

union Frag {
    bf16x8 v;
    unsigned u[4];
    uint4 q;
};

// pack two f32 (as uint bits) -> two bf16 (round-half-up) in one v_perm
__device__ __forceinline__ unsigned pack_bf16_u2(unsigned u0, unsigned u1) {
    u0 += 0x8000u;
    u1 += 0x8000u;
    return __builtin_amdgcn_perm(u1, u0, 0x07060302u);
}

// shifted softplus: softplus(x) - ln2
__device__ __forceinline__ float ssp(float x) {
    float sp = __logf(1.0f + __expf(x));
    sp = (x > 15.0f) ? x : sp;
    return sp - 0.69314718056f;
}

// largest m with off[m] <= g  (off[0]=0, off sorted, n_mols+1 entries)
__device__ __forceinline__ int find_mol(const int* __restrict__ off, int n_mols, int g) {
    int lo = 0, hi = n_mols;
    while (hi - lo > 1) {
        int mid = (lo + hi) >> 1;
        if (off[mid] <= g) lo = mid; else hi = mid;
    }
    return lo;
}

// Block 0: prefix-scan num_atoms (int32, falling back to int64 if the int32
// interpretation doesn't sum to n_atoms) + zero d_out.
// Blocks 1..256: pack W1 -> Bp2, FRAGMENT-ORDER layout: for arr(bf0/bf1),
// w(colgroup), c(kchunk), j: a contiguous 1KB block of 64 lanes x 16 B, so
// gemm-side B loads are lane-sequential (coalescer fast path).
__global__ void prep_kernel(const void* __restrict__ num_atoms_raw,
                            const float* __restrict__ W1,
                            int n_mols, int n_atoms,
                            int* __restrict__ off,
                            unsigned short* __restrict__ Bp2,
                            float* __restrict__ out, int out_n) {
    if (blockIdx.x > 0) {
        int idx = (blockIdx.x - 1) * 256 + threadIdx.x;   // 0..65535
        int arr  = (idx >> 15) & 1;
        int w    = (idx >> 13) & 3;
        int c    = (idx >> 11) & 3;
        int jj   = (idx >> 9)  & 3;
        int lane = (idx >> 3)  & 63;
        int e    = idx & 7;
        int l31 = lane & 31, half = lane >> 5;
        int row = w * 64 + l31 + arr * 32;          // B column index c0
        int k   = c * 64 + jj * 16 + half * 8 + e;  // feature index
        int key = row >> 7, jh = row & 127;
        float f = W1[(size_t)key * FEAT * HID + (size_t)k * HID + jh];
        unsigned u = __float_as_uint(f);
        unsigned r = (u + 0x7FFFu + ((u >> 16) & 1u)) >> 16;   // RNE to bf16
        size_t out_idx = ((size_t)(arr * 4096 + ((w * 4 + c) * 4 + jj) * 64 + lane)) * 8 + e;
        Bp2[out_idx] = (unsigned short)r;
        return;
    }
    // zero the output (atomically accumulated by gemm_fused)
    for (int i = threadIdx.x; i < out_n; i += 256) out[i] = 0.0f;

    __shared__ long long tsum[256];
    __shared__ int csum[257];
    __shared__ int mode_sh;
    int tid = threadIdx.x;
    const int* a32 = (const int*)num_atoms_raw;
    const long long* a64 = (const long long*)num_atoms_raw;
    int chunk = (n_mols + 255) >> 8;
    int lo = tid * chunk;
    if (lo > n_mols) lo = n_mols;
    int hi = lo + chunk;
    if (hi > n_mols) hi = n_mols;
    long long s = 0;
    for (int i = lo; i < hi; ++i) s += (long long)a32[i];
    tsum[tid] = s;
    __syncthreads();
    if (tid == 0) {
        long long t = 0;
        for (int i = 0; i < 256; ++i) t += tsum[i];
        mode_sh = (t == (long long)n_atoms) ? 0 : 1;
    }
    __syncthreads();
    int mode = mode_sh;
    if (mode) {                      // only touch int64 view if int32 failed
        s = 0;
        for (int i = lo; i < hi; ++i) s += a64[i];
        tsum[tid] = s;
    }
    csum[tid] = (int)tsum[tid];
    __syncthreads();
    if (tid == 0) {
        int run = 0;
        for (int i = 0; i < 256; ++i) { int v = csum[i]; csum[i] = run; run += v; }
    }
    __syncthreads();
    int run = csum[tid];
    for (int i = lo; i < hi; ++i) {
        off[i] = run;
        run += mode ? (int)a64[i] : a32[i];
    }
    if (hi >= n_mols) off[n_mols] = run;
}

// Fused: C = s_i @ B (bf16 MFMA, fp32 acc), +b1, shifted-softplus, .W2, +b2,
// segment-sum into out[key][mol] via atomics.
// Block: 256 threads = 4 waves; tile 64 rows x 256 cols; wave = 64x64.
// EVERY global load is lane-sequential (base + lane*16, contiguous 1 KB per
// wave-instruction) -> coalescer fast path. A staged f32 to LDS (padded
// rows), f32->bf16 conversion at frag-read time. One main barrier.
__global__ __launch_bounds__(256, 2)
void gemm_fused(const float* __restrict__ A,
                const uint4* __restrict__ Bp2,
                const float* __restrict__ b1,
                const float* __restrict__ W2,
                const float* __restrict__ b2,
                const int* __restrict__ off,
                float* __restrict__ out,
                int n_atoms, int n_mols) {
    __shared__ unsigned char ldsAraw[64 * LDS_ROW];   // 65 KB, f32 rows padded
    __shared__ float part[4][64];        // [wn][row]
    __shared__ float molacc[NKEYS][4];

    const int tid  = threadIdx.x;
    const int lane = tid & 63;
    const int wn   = tid >> 6;           // 0..3
    const int l31  = lane & 31;
    const int half = lane >> 5;          // 0/1
    const int m0   = blockIdx.x * 64;

    // ---- A staging: wave wn stages rows wn*16..wn*16+15.
    // Each row: one lane-sequential global_load_dwordx4 (lane*16) + one
    // lane-sequential ds_write_b128. Loads burst ahead of stores.
    {
        uint4 q[16];
        #pragma unroll
        for (int i = 0; i < 16; ++i) {
            const int r = wn * 16 + i;
            int grow = m0 + r;
            if (grow > n_atoms - 1) grow = n_atoms - 1;
            q[i] = *(const uint4*)(A + (size_t)grow * FEAT + lane * 4);
        }
        #pragma unroll
        for (int i = 0; i < 16; ++i) {
            const int r = wn * 16 + i;
            *(uint4*)(ldsAraw + r * LDS_ROW + lane * 16) = q[i];
        }
    }

    // ---- B prefetch, chunks 0,1 (fragment-order: lane-sequential 1KB blocks)
    const uint4* B0 = Bp2;               // bf0 frags: [(w*4+c)*4+j][lane]
    const uint4* B1 = Bp2 + 4096;        // bf1 frags
    Frag bf0[2][4], bf1[2][4];
    #pragma unroll
    for (int s = 0; s < 2; ++s)
        #pragma unroll
        for (int j = 0; j < 4; ++j) {
            bf0[s][j].q = B0[(((wn * 4) + s) * 4 + j) * 64 + lane];
            bf1[s][j].q = B1[(((wn * 4) + s) * 4 + j) * 64 + lane];
        }

    __syncthreads();                     // the ONLY main-loop barrier

    // ---- compute phase: LDS f32 -> bf16 frags -> MFMA
    const unsigned char* rbp0 = ldsAraw + l31 * LDS_ROW;
    const unsigned char* rbp1 = ldsAraw + (l31 + 32) * LDS_ROW;

    f32x16 acc00 = 0.0f, acc01 = 0.0f, acc10 = 0.0f, acc11 = 0.0f;

    #pragma unroll
    for (int c = 0; c < 4; ++c) {
        const int slot = c & 1;
        #pragma unroll
        for (int j = 0; j < 4; ++j) {
            const int g0 = (c * 16 + j * 4 + half * 2) * 16;   // byte offset
            uint4 q0 = *(const uint4*)(rbp0 + g0);
            uint4 q1 = *(const uint4*)(rbp0 + g0 + 16);
            uint4 r0 = *(const uint4*)(rbp1 + g0);
            uint4 r1 = *(const uint4*)(rbp1 + g0 + 16);
            Frag a0, a1;
            a0.u[0] = pack_bf16_u2(q0.x, q0.y);
            a0.u[1] = pack_bf16_u2(q0.z, q0.w);
            a0.u[2] = pack_bf16_u2(q1.x, q1.y);
            a0.u[3] = pack_bf16_u2(q1.z, q1.w);
            a1.u[0] = pack_bf16_u2(r0.x, r0.y);
            a1.u[1] = pack_bf16_u2(r0.z, r0.w);
            a1.u[2] = pack_bf16_u2(r1.x, r1.y);
            a1.u[3] = pack_bf16_u2(r1.z, r1.w);
            acc00 = __builtin_amdgcn_mfma_f32_32x32x16_bf16(a0.v, bf0[slot][j].v, acc00, 0, 0, 0);
            acc01 = __builtin_amdgcn_mfma_f32_32x32x16_bf16(a0.v, bf1[slot][j].v, acc01, 0, 0, 0);
            acc10 = __builtin_amdgcn_mfma_f32_32x32x16_bf16(a1.v, bf0[slot][j].v, acc10, 0, 0, 0);
            acc11 = __builtin_amdgcn_mfma_f32_32x32x16_bf16(a1.v, bf1[slot][j].v, acc11, 0, 0, 0);
        }
        if (c + 2 < 4) {                 // refill this B slot with chunk c+2
            #pragma unroll
            for (int j = 0; j < 4; ++j) {
                bf0[slot][j].q = B0[(((wn * 4) + (c + 2)) * 4 + j) * 64 + lane];
                bf1[slot][j].q = B1[(((wn * 4) + (c + 2)) * 4 + j) * 64 + lane];
            }
        }
    }

    if (tid < NKEYS * 4) molacc[tid >> 2][tid & 3] = 0.0f;

    const int c0 = wn * 64 + l31;
    float b1c0 = b1[c0], b1c1 = b1[c0 + 32];
    float w2c0 = W2[c0], w2c1 = W2[c0 + 32];

    // epilogue: act + .W2, column-reduce per row, stash in LDS
    #pragma unroll
    for (int rt = 0; rt < 2; ++rt) {
        const f32x16& Ac0 = rt ? acc10 : acc00;
        const f32x16& Ac1 = rt ? acc11 : acc01;
        #pragma unroll
        for (int r = 0; r < 16; ++r) {
            float t = ssp(Ac0[r] + b1c0) * w2c0 + ssp(Ac1[r] + b1c1) * w2c1;
            t += __shfl_xor(t, 1);
            t += __shfl_xor(t, 2);
            t += __shfl_xor(t, 4);
            t += __shfl_xor(t, 8);
            t += __shfl_xor(t, 16);
            if (l31 == r) {
                int row = rt * 32 + (r & 3) + 8 * (r >> 2) + 4 * half;
                part[wn][row] = t;
            }
        }
    }
    __syncthreads();

    if (tid < NKEYS * 64) {
        int key = tid >> 6, r = tid & 63;
        int gm = m0 + r;
        if (gm < n_atoms) {
            float val = part[2 * key][r] + part[2 * key + 1][r] + b2[key];
            int mol  = find_mol(off, n_mols, gm);
            int mol0 = find_mol(off, n_mols, m0);
            int ml = mol - mol0;
            if (ml < 4) atomicAdd(&molacc[key][ml], val);
            else        atomicAdd(&out[(size_t)key * n_mols + mol], val);
        }
    }
    __syncthreads();

    if (tid < NKEYS * 4) {
        int key = tid >> 2, ml = tid & 3;
        int mol0 = find_mol(off, n_mols, m0);
        int mol = mol0 + ml;
        if (mol < n_mols) {
            float v = molacc[key][ml];
            if (v != 0.0f) atomicAdd(&out[(size_t)key * n_mols + mol], v);
        }
    }
}

extern "C" void kernel_launch(void* const* d_in, const int* in_sizes, int n_in,
                              void* d_out, int out_size, void* d_ws, size_t ws_size,
                              hipStream_t stream) {
    const float* s_i      = (const float*)d_in[0];
    // d_in[1] = xyz: unused by the reference output
    const void*  num_atoms = d_in[2];
    const float* W1 = (const float*)d_in[3];
    const float* b1 = (const float*)d_in[4];
    const float* W2 = (const float*)d_in[5];
    const float* b2 = (const float*)d_in[6];
    int n_atoms = in_sizes[0] / FEAT;
    int n_mols  = in_sizes[2];
    float* out = (float*)d_out;

    int* off = (int*)d_ws;
    size_t off_bytes = (((size_t)(n_mols + 1) * 4) + 255) & ~(size_t)255;
    unsigned short* Bp2 = (unsigned short*)((char*)d_ws + off_bytes);

    int pack_blocks = (NKEYS * HID * FEAT) / 256;   // 256
    prep_kernel<<<1 + pack_blocks, 256, 0, stream>>>(num_atoms, W1, n_mols, n_atoms,
                                                     off, Bp2, out, out_size);

    int gblocks = (n_atoms + 63) / 64;
    gemm_fused<<<gblocks, 256, 0, stream>>>(s_i, (const uint4*)Bp2, b1, W2, b2, off,
                                            out, n_atoms, n_mols);
}

// Round 6
// 382.950 us; speedup vs baseline: 1.0137x; 1.0137x over previous
//
#include <hip/hip_runtime.h>

#define FEAT 256
#define HID 128
#define NKEYS 2
#define KSTRIDE 258    // transpose LDS row stride in floats (breaks bank alias)
#define LDS_ROW 1040   // fallback kernel LDS row stride (bytes)

typedef __bf16 bf16x8 __attribute__((ext_vector_type(8)));
typedef float f32x16 __attribute__((ext_vector_type(16)));

union Frag {
    bf16x8 v;
    unsigned u[4];
    uint4 q;
};

// pack two f32 (as uint bits) -> two bf16 (round-half-up) in one v_perm
__device__ __forceinline__ unsigned pack_bf16_u2(unsigned u0, unsigned u1) {
    u0 += 0x8000u;
    u1 += 0x8000u;
    return __builtin_amdgcn_perm(u1, u0, 0x07060302u);
}

// shifted softplus: softplus(x) - ln2
__device__ __forceinline__ float ssp(float x) {
    float sp = __logf(1.0f + __expf(x));
    sp = (x > 15.0f) ? x : sp;
    return sp - 0.69314718056f;
}

// largest m with off[m] <= g  (off[0]=0, off sorted, n_mols+1 entries)
__device__ __forceinline__ int find_mol(const int* __restrict__ off, int n_mols, int g) {
    int lo = 0, hi = n_mols;
    while (hi - lo > 1) {
        int mid = (lo + hi) >> 1;
        if (off[mid] <= g) lo = mid; else hi = mid;
    }
    return lo;
}

// Block 0: prefix-scan num_atoms (int32, falling back to int64 if the int32
// interpretation doesn't sum to n_atoms) + zero d_out.
// Blocks 1..256: pack W1 -> Bp2, FRAGMENT-ORDER layout: frag (arr, wn, ks) is
// a contiguous 1KB block of 64 lanes x 16 B (lane-sequential loads gemm-side).
__global__ void prep_kernel(const void* __restrict__ num_atoms_raw,
                            const float* __restrict__ W1,
                            int n_mols, int n_atoms,
                            int* __restrict__ off,
                            unsigned short* __restrict__ Bp2,
                            float* __restrict__ out, int out_n) {
    if (blockIdx.x > 0) {
        int idx = (blockIdx.x - 1) * 256 + threadIdx.x;   // 0..65535
        int arr  = (idx >> 15) & 1;
        int w    = (idx >> 13) & 3;
        int ks   = (idx >> 9)  & 15;
        int lane = (idx >> 3)  & 63;
        int e    = idx & 7;
        int l31 = lane & 31, half = lane >> 5;
        int row = w * 64 + l31 + arr * 32;          // B column index c0
        int k   = ks * 16 + half * 8 + e;           // feature index
        int key = row >> 7, jh = row & 127;
        float f = W1[(size_t)key * FEAT * HID + (size_t)k * HID + jh];
        unsigned u = __float_as_uint(f);
        unsigned r = (u + 0x7FFFu + ((u >> 16) & 1u)) >> 16;   // RNE to bf16
        size_t out_idx = ((size_t)(arr * 4096 + (w * 16 + ks) * 64 + lane)) * 8 + e;
        Bp2[out_idx] = (unsigned short)r;
        return;
    }
    // zero the output (atomically accumulated by gemm)
    for (int i = threadIdx.x; i < out_n; i += 256) out[i] = 0.0f;

    __shared__ long long tsum[256];
    __shared__ int csum[257];
    __shared__ int mode_sh;
    int tid = threadIdx.x;
    const int* a32 = (const int*)num_atoms_raw;
    const long long* a64 = (const long long*)num_atoms_raw;
    int chunk = (n_mols + 255) >> 8;
    int lo = tid * chunk;
    if (lo > n_mols) lo = n_mols;
    int hi = lo + chunk;
    if (hi > n_mols) hi = n_mols;
    long long s = 0;
    for (int i = lo; i < hi; ++i) s += (long long)a32[i];
    tsum[tid] = s;
    __syncthreads();
    if (tid == 0) {
        long long t = 0;
        for (int i = 0; i < 256; ++i) t += tsum[i];
        mode_sh = (t == (long long)n_atoms) ? 0 : 1;
    }
    __syncthreads();
    int mode = mode_sh;
    if (mode) {                      // only touch int64 view if int32 failed
        s = 0;
        for (int i = lo; i < hi; ++i) s += a64[i];
        tsum[tid] = s;
    }
    csum[tid] = (int)tsum[tid];
    __syncthreads();
    if (tid == 0) {
        int run = 0;
        for (int i = 0; i < 256; ++i) { int v = csum[i]; csum[i] = run; run += v; }
    }
    __syncthreads();
    int run = csum[tid];
    for (int i = lo; i < hi; ++i) {
        off[i] = run;
        run += mode ? (int)a64[i] : a32[i];
    }
    if (hi >= n_mols) off[n_mols] = run;
}

// Streaming pass: s_i f32 row-major -> At bf16 in MFMA A-fragment order.
// Block = 32 atoms (rt = blockIdx). Coalesced 1KB-per-wave-instr reads,
// LDS bounce (row stride 258 floats), lane-sequential 1KB fragment writes.
// 33 KB LDS -> 4 blocks/CU -> 16 waves/CU of nearly pure streaming.
__global__ __launch_bounds__(256, 4)
void transpose_kernel(const float* __restrict__ A, uint4* __restrict__ At,
                      int n_atoms) {
    __shared__ float ldsF[32 * KSTRIDE];
    const int tid  = threadIdx.x;
    const int w    = tid >> 6;
    const int lane = tid & 63;
    const int rt   = blockIdx.x;
    const int a0   = rt * 32;

    // phase 1: each wave-instr reads one full 1 KB row (lane-sequential)
    #pragma unroll
    for (int i = 0; i < 8; ++i) {
        int atom = i * 4 + w;
        int ga = a0 + atom;
        if (ga > n_atoms - 1) ga = n_atoms - 1;
        float4 v = *(const float4*)(A + (size_t)ga * FEAT + lane * 4);
        float* d = &ldsF[atom * KSTRIDE + lane * 4];
        *(float2*)(d)     = make_float2(v.x, v.y);
        *(float2*)(d + 2) = make_float2(v.z, v.w);
    }
    __syncthreads();

    // phase 2: assemble fragments; frag f: lane holds atom=l31, k=f*16+half*8..+8
    #pragma unroll
    for (int e = 0; e < 4; ++e) {
        int f    = e * 4 + w;            // kstep 0..15
        int atom = lane & 31;
        int kb   = f * 16 + (lane >> 5) * 8;
        const float* s = &ldsF[atom * KSTRIDE + kb];
        uint4 p;
        p.x = pack_bf16_u2(__float_as_uint(s[0]), __float_as_uint(s[1]));
        p.y = pack_bf16_u2(__float_as_uint(s[2]), __float_as_uint(s[3]));
        p.z = pack_bf16_u2(__float_as_uint(s[4]), __float_as_uint(s[5]));
        p.w = pack_bf16_u2(__float_as_uint(s[6]), __float_as_uint(s[7]));
        At[((size_t)rt * 16 + f) * 64 + lane] = p;   // lane-seq 1 KB store
    }
}

// GEMM consumer: NO LDS in K-loop, NO barrier, NO conversion. Per wave:
// 16 A-frag + 32 B-frag lane-sequential 1 KB loads, 32 MFMAs. Fully
// compiler-pipelineable. Block = 32 atoms x 256 cols (4 waves x 64 cols).
__global__ __launch_bounds__(256, 3)
void gemm_frag(const uint4* __restrict__ At,
               const uint4* __restrict__ Bp2,
               const float* __restrict__ b1,
               const float* __restrict__ W2,
               const float* __restrict__ b2,
               const int* __restrict__ off,
               float* __restrict__ out,
               int n_atoms, int n_mols) {
    __shared__ float part[4][32];
    __shared__ float molacc[NKEYS][4];

    const int tid  = threadIdx.x;
    const int lane = tid & 63;
    const int wn   = tid >> 6;
    const int l31  = lane & 31;
    const int half = lane >> 5;
    const int rt   = blockIdx.x;
    const int m0   = rt * 32;

    const uint4* Ab = At + (size_t)rt * 16 * 64 + lane;
    const uint4* B0 = Bp2 + (size_t)(wn * 16) * 64 + lane;
    const uint4* B1 = Bp2 + 4096 + (size_t)(wn * 16) * 64 + lane;

    f32x16 acc0 = 0.0f, acc1 = 0.0f;

    #pragma unroll
    for (int ks = 0; ks < 16; ++ks) {
        Frag a, q0, q1;
        a.q  = Ab[ks * 64];
        q0.q = B0[ks * 64];
        q1.q = B1[ks * 64];
        acc0 = __builtin_amdgcn_mfma_f32_32x32x16_bf16(a.v, q0.v, acc0, 0, 0, 0);
        acc1 = __builtin_amdgcn_mfma_f32_32x32x16_bf16(a.v, q1.v, acc1, 0, 0, 0);
    }

    if (tid < NKEYS * 4) molacc[tid >> 2][tid & 3] = 0.0f;

    const int c0 = wn * 64 + l31;
    float b1c0 = b1[c0], b1c1 = b1[c0 + 32];
    float w2c0 = W2[c0], w2c1 = W2[c0 + 32];

    // act + .W2, column-reduce (32 cols per half), stash per-row partials
    #pragma unroll
    for (int r = 0; r < 16; ++r) {
        float t = ssp(acc0[r] + b1c0) * w2c0 + ssp(acc1[r] + b1c1) * w2c1;
        t += __shfl_xor(t, 1);
        t += __shfl_xor(t, 2);
        t += __shfl_xor(t, 4);
        t += __shfl_xor(t, 8);
        t += __shfl_xor(t, 16);
        if (l31 == r) {
            int row = (r & 3) + 8 * (r >> 2) + 4 * half;
            part[wn][row] = t;
        }
    }
    __syncthreads();

    if (tid < NKEYS * 32) {
        int key = tid >> 5, r = tid & 31;
        int gm = m0 + r;
        if (gm < n_atoms) {
            float val = part[2 * key][r] + part[2 * key + 1][r] + b2[key];
            int mol  = find_mol(off, n_mols, gm);
            int mol0 = find_mol(off, n_mols, m0);
            int ml = mol - mol0;
            if (ml < 4) atomicAdd(&molacc[key][ml], val);
            else        atomicAdd(&out[(size_t)key * n_mols + mol], val);
        }
    }
    __syncthreads();

    if (tid < NKEYS * 4) {
        int key = tid >> 2, ml = tid & 3;
        int mol0 = find_mol(off, n_mols, m0);
        int mol = mol0 + ml;
        if (mol < n_mols) {
            float v = molacc[key][ml];
            if (v != 0.0f) atomicAdd(&out[(size_t)key * n_mols + mol], v);
        }
    }
}

// ---- fallback (R5 structure, correct at 176 us) if ws can't hold At ----
__global__ __launch_bounds__(256, 2)
void gemm_fallback(const float* __restrict__ A,
                   const uint4* __restrict__ Bp2,
                   const float* __restrict__ b1,
                   const float* __restrict__ W2,
                   const float* __restrict__ b2,
                   const int* __restrict__ off,
                   float* __restrict__ out,
                   int n_atoms, int n_mols) {
    __shared__ unsigned char ldsAraw[64 * LDS_ROW];
    __shared__ float part[4][64];
    __shared__ float molacc[NKEYS][4];

    const int tid  = threadIdx.x;
    const int lane = tid & 63;
    const int wn   = tid >> 6;
    const int l31  = lane & 31;
    const int half = lane >> 5;
    const int m0   = blockIdx.x * 64;

    {
        uint4 q[16];
        #pragma unroll
        for (int i = 0; i < 16; ++i) {
            const int r = wn * 16 + i;
            int grow = m0 + r;
            if (grow > n_atoms - 1) grow = n_atoms - 1;
            q[i] = *(const uint4*)(A + (size_t)grow * FEAT + lane * 4);
        }
        #pragma unroll
        for (int i = 0; i < 16; ++i) {
            const int r = wn * 16 + i;
            *(uint4*)(ldsAraw + r * LDS_ROW + lane * 16) = q[i];
        }
    }

    const uint4* B0 = Bp2;
    const uint4* B1 = Bp2 + 4096;
    Frag bf0[2][4], bf1[2][4];
    #pragma unroll
    for (int s = 0; s < 2; ++s)
        #pragma unroll
        for (int j = 0; j < 4; ++j) {
            bf0[s][j].q = B0[(wn * 16 + s * 4 + j) * 64 + lane];
            bf1[s][j].q = B1[(wn * 16 + s * 4 + j) * 64 + lane];
        }

    __syncthreads();

    const unsigned char* rbp0 = ldsAraw + l31 * LDS_ROW;
    const unsigned char* rbp1 = ldsAraw + (l31 + 32) * LDS_ROW;

    f32x16 acc00 = 0.0f, acc01 = 0.0f, acc10 = 0.0f, acc11 = 0.0f;

    #pragma unroll
    for (int c = 0; c < 4; ++c) {
        const int slot = c & 1;
        #pragma unroll
        for (int j = 0; j < 4; ++j) {
            const int g0 = (c * 16 + j * 4 + half * 2) * 16;
            uint4 q0 = *(const uint4*)(rbp0 + g0);
            uint4 q1 = *(const uint4*)(rbp0 + g0 + 16);
            uint4 r0 = *(const uint4*)(rbp1 + g0);
            uint4 r1 = *(const uint4*)(rbp1 + g0 + 16);
            Frag a0, a1;
            a0.u[0] = pack_bf16_u2(q0.x, q0.y);
            a0.u[1] = pack_bf16_u2(q0.z, q0.w);
            a0.u[2] = pack_bf16_u2(q1.x, q1.y);
            a0.u[3] = pack_bf16_u2(q1.z, q1.w);
            a1.u[0] = pack_bf16_u2(r0.x, r0.y);
            a1.u[1] = pack_bf16_u2(r0.z, r0.w);
            a1.u[2] = pack_bf16_u2(r1.x, r1.y);
            a1.u[3] = pack_bf16_u2(r1.z, r1.w);
            acc00 = __builtin_amdgcn_mfma_f32_32x32x16_bf16(a0.v, bf0[slot][j].v, acc00, 0, 0, 0);
            acc01 = __builtin_amdgcn_mfma_f32_32x32x16_bf16(a0.v, bf1[slot][j].v, acc01, 0, 0, 0);
            acc10 = __builtin_amdgcn_mfma_f32_32x32x16_bf16(a1.v, bf0[slot][j].v, acc10, 0, 0, 0);
            acc11 = __builtin_amdgcn_mfma_f32_32x32x16_bf16(a1.v, bf1[slot][j].v, acc11, 0, 0, 0);
        }
        if (c + 2 < 4) {
            #pragma unroll
            for (int j = 0; j < 4; ++j) {
                bf0[slot][j].q = B0[(wn * 16 + (c + 2) * 4 + j) * 64 + lane];
                bf1[slot][j].q = B1[(wn * 16 + (c + 2) * 4 + j) * 64 + lane];
            }
        }
    }

    if (tid < NKEYS * 4) molacc[tid >> 2][tid & 3] = 0.0f;

    const int c0 = wn * 64 + l31;
    float b1c0 = b1[c0], b1c1 = b1[c0 + 32];
    float w2c0 = W2[c0], w2c1 = W2[c0 + 32];

    #pragma unroll
    for (int rt2 = 0; rt2 < 2; ++rt2) {
        const f32x16& Ac0 = rt2 ? acc10 : acc00;
        const f32x16& Ac1 = rt2 ? acc11 : acc01;
        #pragma unroll
        for (int r = 0; r < 16; ++r) {
            float t = ssp(Ac0[r] + b1c0) * w2c0 + ssp(Ac1[r] + b1c1) * w2c1;
            t += __shfl_xor(t, 1);
            t += __shfl_xor(t, 2);
            t += __shfl_xor(t, 4);
            t += __shfl_xor(t, 8);
            t += __shfl_xor(t, 16);
            if (l31 == r) {
                int row = rt2 * 32 + (r & 3) + 8 * (r >> 2) + 4 * half;
                part[wn][row] = t;
            }
        }
    }
    __syncthreads();

    if (tid < NKEYS * 64) {
        int key = tid >> 6, r = tid & 63;
        int gm = m0 + r;
        if (gm < n_atoms) {
            float val = part[2 * key][r] + part[2 * key + 1][r] + b2[key];
            int mol  = find_mol(off, n_mols, gm);
            int mol0 = find_mol(off, n_mols, m0);
            int ml = mol - mol0;
            if (ml < 4) atomicAdd(&molacc[key][ml], val);
            else        atomicAdd(&out[(size_t)key * n_mols + mol], val);
        }
    }
    __syncthreads();

    if (tid < NKEYS * 4) {
        int key = tid >> 2, ml = tid & 3;
        int mol0 = find_mol(off, n_mols, m0);
        int mol = mol0 + ml;
        if (mol < n_mols) {
            float v = molacc[key][ml];
            if (v != 0.0f) atomicAdd(&out[(size_t)key * n_mols + mol], v);
        }
    }
}

extern "C" void kernel_launch(void* const* d_in, const int* in_sizes, int n_in,
                              void* d_out, int out_size, void* d_ws, size_t ws_size,
                              hipStream_t stream) {
    const float* s_i      = (const float*)d_in[0];
    // d_in[1] = xyz: unused by the reference output
    const void*  num_atoms = d_in[2];
    const float* W1 = (const float*)d_in[3];
    const float* b1 = (const float*)d_in[4];
    const float* W2 = (const float*)d_in[5];
    const float* b2 = (const float*)d_in[6];
    int n_atoms = in_sizes[0] / FEAT;
    int n_mols  = in_sizes[2];
    float* out = (float*)d_out;

    int* off = (int*)d_ws;
    size_t off_bytes = (((size_t)(n_mols + 1) * 4) + 255) & ~(size_t)255;
    unsigned short* Bp2 = (unsigned short*)((char*)d_ws + off_bytes);
    const size_t bp2_bytes = 131072;

    int rtcnt = (n_atoms + 31) / 32;
    size_t at_bytes = (size_t)rtcnt * 16384;
    size_t need = off_bytes + bp2_bytes + at_bytes;

    prep_kernel<<<257, 256, 0, stream>>>(num_atoms, W1, n_mols, n_atoms,
                                         off, Bp2, out, out_size);

    if (ws_size >= need) {
        uint4* At = (uint4*)((char*)d_ws + off_bytes + bp2_bytes);
        transpose_kernel<<<rtcnt, 256, 0, stream>>>(s_i, At, n_atoms);
        gemm_frag<<<rtcnt, 256, 0, stream>>>(At, (const uint4*)Bp2, b1, W2, b2,
                                             off, out, n_atoms, n_mols);
    } else {
        int gblocks = (n_atoms + 63) / 64;
        gemm_fallback<<<gblocks, 256, 0, stream>>>(s_i, (const uint4*)Bp2, b1, W2,
                                                   b2, off, out, n_atoms, n_mols);
    }
}